// Round 2
// baseline (970.025 us; speedup 1.0000x reference)
//
#include <hip/hip_runtime.h>
#include <math.h>

#define DEVFN __device__ __forceinline__

constexpr int Bc  = 48;     // batch
constexpr int HH  = 49;     // H = W
constexpr int CC  = 128;    // channels
constexpr int NHd = 4;      // heads
constexpr int HD  = 32;     // head dim
constexpr int WSz = 7;      // window
constexpr int SSz = 3;      // shift
constexpr int nWd = 49;     // windows per image
constexpr int NT  = 49;     // tokens per window
constexpr int LL  = HH*HH;  // 2401
constexpr int MR  = Bc*nWd*NT; // 115248 rows

// map windowed row (b, win, t) -> source/destination token index (shift applied)
DEVFN int win_row_to_token(int r){
  int b   = r / (nWd*NT);
  int rem = r - b*(nWd*NT);
  int win = rem / NT;
  int t   = rem - win*NT;
  int hs  = (win/7)*7 + t/7;
  int ws_ = (win%7)*7 + t%7;
  int h = hs + SSz; if (h >= HH) h -= HH;
  int w = ws_ + SSz; if (w >= HH) w -= HH;
  return b*LL + h*HH + w;
}

// region id for shift mask: window index win (0..48), token tok (0..48)
DEVFN int rgn(int win, int tok){
  int hh = (win/7)*7 + tok/7;
  int ww = (win%7)*7 + tok%7;
  int rh = hh < 42 ? 0 : (hh < 46 ? 1 : 2);
  int rw = ww < 42 ? 0 : (ww < 46 ? 1 : 2);
  return rh*3 + rw;
}

// -------- LN1 + cyclic shift + window partition gather --------
__global__ __launch_bounds__(256) void ln1_gather(const float* __restrict__ x,
                                                  const float* __restrict__ w,
                                                  const float* __restrict__ b,
                                                  float* __restrict__ xw){
  int row  = blockIdx.x*4 + (threadIdx.x >> 6);
  int lane = threadIdx.x & 63;
  if (row >= MR) return;
  int token = win_row_to_token(row);
  const float* xp = x + (size_t)token*CC;
  float2 v = *(const float2*)(xp + lane*2);
  float s  = v.x + v.y;
  float s2 = v.x*v.x + v.y*v.y;
  #pragma unroll
  for (int off = 32; off; off >>= 1){ s += __shfl_xor(s, off); s2 += __shfl_xor(s2, off); }
  float mean = s * (1.f/CC);
  float var  = s2 * (1.f/CC) - mean*mean;
  float rstd = rsqrtf(var + 1e-5f);
  float2 o;
  o.x = (v.x - mean)*rstd*w[lane*2+0] + b[lane*2+0];
  o.y = (v.y - mean)*rstd*w[lane*2+1] + b[lane*2+1];
  *(float2*)(xw + (size_t)row*CC + lane*2) = o;
}

// -------- LN2 row stats (over x2 = d_out) --------
__global__ __launch_bounds__(256) void ln2_stats(const float* __restrict__ x2,
                                                 float* __restrict__ stats){
  int row  = blockIdx.x*4 + (threadIdx.x >> 6);
  int lane = threadIdx.x & 63;
  if (row >= MR) return;
  float2 v = *(const float2*)(x2 + (size_t)row*CC + lane*2);
  float s  = v.x + v.y;
  float s2 = v.x*v.x + v.y*v.y;
  #pragma unroll
  for (int off = 32; off; off >>= 1){ s += __shfl_xor(s, off); s2 += __shfl_xor(s2, off); }
  float mean = s * (1.f/CC);
  float var  = s2 * (1.f/CC) - mean*mean;
  if (lane == 0){
    stats[2*row+0] = mean;
    stats[2*row+1] = rsqrtf(var + 1e-5f);
  }
}

// -------- windowed attention: one block per window, one wave per head --------
__global__ __launch_bounds__(256) void attn_kernel(const float* __restrict__ qkv,
                                                   const float* __restrict__ rpb,
                                                   float* __restrict__ attno){
  __shared__ float k_s[NHd][NT*HD];
  __shared__ float v_s[NHd][NT*HD];
  __shared__ float q_s[NHd][NT*(HD+1)];
  __shared__ float rpb_s[169*NHd];
  int win  = blockIdx.x;          // 0..2351
  int h    = threadIdx.x >> 6;    // head
  int lane = threadIdx.x & 63;

  for (int i = threadIdx.x; i < 169*NHd; i += 256) rpb_s[i] = rpb[i];

  const float* base = qkv + (size_t)win*NT*384;
  for (int i = lane; i < NT*HD; i += 64){
    int j = i >> 5, d = i & 31;
    float qv = base[j*384 +   0 + h*HD + d];
    float kv = base[j*384 + 128 + h*HD + d];
    float vv = base[j*384 + 256 + h*HD + d];
    q_s[h][j*(HD+1)+d] = qv;
    k_s[h][i] = kv;
    v_s[h][i] = vv;
  }
  __syncthreads();

  int i = lane;
  if (i >= NT) return;

  float q[HD];
  #pragma unroll
  for (int d = 0; d < HD; ++d) q[d] = q_s[h][i*(HD+1)+d] * 0.17677669529663689f;

  int wmod = win % nWd;           // window index within image
  int yi = i/7, xi = i%7;

  float s[NT];
  #pragma unroll
  for (int j = 0; j < NT; ++j){
    float dot = 0.f;
    #pragma unroll
    for (int d4 = 0; d4 < HD/4; ++d4){
      float4 kv = *(const float4*)&k_s[h][j*HD + d4*4];
      dot = fmaf(q[d4*4+0], kv.x, dot);
      dot = fmaf(q[d4*4+1], kv.y, dot);
      dot = fmaf(q[d4*4+2], kv.z, dot);
      dot = fmaf(q[d4*4+3], kv.w, dot);
    }
    int yj = j/7, xj = j%7;
    int idx = (yi - yj + 6)*13 + (xi - xj + 6);
    float bias = rpb_s[idx*NHd + h];
    float mask = (rgn(wmod, j) != rgn(i, j)) ? -100.f : 0.f;
    s[j] = dot + bias + mask;
  }

  float m = -1e30f;
  #pragma unroll
  for (int j = 0; j < NT; ++j) m = fmaxf(m, s[j]);
  float sum = 0.f;
  #pragma unroll
  for (int j = 0; j < NT; ++j){ s[j] = __expf(s[j]-m); sum += s[j]; }
  float inv = 1.f/sum;

  float o[HD];
  #pragma unroll
  for (int d = 0; d < HD; ++d) o[d] = 0.f;
  #pragma unroll
  for (int j = 0; j < NT; ++j){
    float p = s[j]*inv;
    #pragma unroll
    for (int d4 = 0; d4 < HD/4; ++d4){
      float4 vv = *(const float4*)&v_s[h][j*HD + d4*4];
      o[d4*4+0] = fmaf(p, vv.x, o[d4*4+0]);
      o[d4*4+1] = fmaf(p, vv.y, o[d4*4+1]);
      o[d4*4+2] = fmaf(p, vv.z, o[d4*4+2]);
      o[d4*4+3] = fmaf(p, vv.w, o[d4*4+3]);
    }
  }

  float* op = attno + ((size_t)win*NT + i)*CC + h*HD;
  #pragma unroll
  for (int d4 = 0; d4 < HD/4; ++d4)
    *(float4*)(op + d4*4) = make_float4(o[d4*4+0], o[d4*4+1], o[d4*4+2], o[d4*4+3]);
}

// -------- generic tiled GEMM: Out = epilogue(A @ W^T + bias) --------
// MODE 0: qkv    (A=xw,      write qkv[r*384+col])
// MODE 1: proj   (A=attno,   Out[token]=X[token]+res, token=map(r))
// MODE 2: fc1    (A=x2 w/ LN(stats,lnw,lnb), GELU, write hid[r*512+col])
// MODE 3: fc2    (A=hid,     Out[r] += res  (in-place residual))
template<int MODE, int Ntot, int KK>
__global__ __launch_bounds__(256) void gemm(const float* __restrict__ A,
                                            const float* __restrict__ Wm,
                                            const float* __restrict__ bias,
                                            float* __restrict__ Out,
                                            const float* __restrict__ X,
                                            const float* __restrict__ stats,
                                            const float* __restrict__ lnw,
                                            const float* __restrict__ lnb){
  constexpr int BM = 64, BN = 64, BK = 16, LDT = 68;
  __shared__ float As[BK][LDT];
  __shared__ float Ws[BK][LDT];
  int tid  = threadIdx.x;
  int row0 = blockIdx.x*BM, col0 = blockIdx.y*BN;
  int tx = tid & 15, ty = tid >> 4;
  int la_row = tid >> 2;         // 0..63
  int la_k4  = (tid & 3) * 4;    // 0,4,8,12
  float acc[4][4] = {};

  for (int k0 = 0; k0 < KK; k0 += BK){
    int ar = row0 + la_row;
    float4 av = make_float4(0.f,0.f,0.f,0.f);
    if (ar < MR){
      av = *(const float4*)(A + (size_t)ar*KK + k0 + la_k4);
      if constexpr (MODE == 2){
        float mean = stats[2*ar+0], rstd = stats[2*ar+1];
        int kb = k0 + la_k4;
        av.x = (av.x-mean)*rstd*lnw[kb+0] + lnb[kb+0];
        av.y = (av.y-mean)*rstd*lnw[kb+1] + lnb[kb+1];
        av.z = (av.z-mean)*rstd*lnw[kb+2] + lnb[kb+2];
        av.w = (av.w-mean)*rstd*lnw[kb+3] + lnb[kb+3];
      }
    }
    As[la_k4+0][la_row] = av.x;
    As[la_k4+1][la_row] = av.y;
    As[la_k4+2][la_row] = av.z;
    As[la_k4+3][la_row] = av.w;
    float4 wv = *(const float4*)(Wm + (size_t)(col0+la_row)*KK + k0 + la_k4);
    Ws[la_k4+0][la_row] = wv.x;
    Ws[la_k4+1][la_row] = wv.y;
    Ws[la_k4+2][la_row] = wv.z;
    Ws[la_k4+3][la_row] = wv.w;
    __syncthreads();
    #pragma unroll
    for (int kk = 0; kk < BK; ++kk){
      float4 a4 = *(const float4*)&As[kk][ty*4];
      float4 b4 = *(const float4*)&Ws[kk][tx*4];
      float avv[4] = {a4.x,a4.y,a4.z,a4.w};
      float bvv[4] = {b4.x,b4.y,b4.z,b4.w};
      #pragma unroll
      for (int ii = 0; ii < 4; ++ii)
        #pragma unroll
        for (int jj = 0; jj < 4; ++jj)
          acc[ii][jj] = fmaf(avv[ii], bvv[jj], acc[ii][jj]);
    }
    __syncthreads();
  }

  int col = col0 + tx*4;
  float4 bv = *(const float4*)(bias + col);
  #pragma unroll
  for (int ii = 0; ii < 4; ++ii){
    int r = row0 + ty*4 + ii;
    if (r >= MR) continue;
    float4 res;
    res.x = acc[ii][0] + bv.x;
    res.y = acc[ii][1] + bv.y;
    res.z = acc[ii][2] + bv.z;
    res.w = acc[ii][3] + bv.w;
    if constexpr (MODE == 0){
      *(float4*)(Out + (size_t)r*Ntot + col) = res;
    } else if constexpr (MODE == 1){
      int tok = win_row_to_token(r);
      float4 xv = *(const float4*)(X + (size_t)tok*CC + col);
      res.x += xv.x; res.y += xv.y; res.z += xv.z; res.w += xv.w;
      *(float4*)(Out + (size_t)tok*CC + col) = res;
    } else if constexpr (MODE == 2){
      res.x = 0.5f*res.x*(1.f + erff(res.x*0.70710678118654752f));
      res.y = 0.5f*res.y*(1.f + erff(res.y*0.70710678118654752f));
      res.z = 0.5f*res.z*(1.f + erff(res.z*0.70710678118654752f));
      res.w = 0.5f*res.w*(1.f + erff(res.w*0.70710678118654752f));
      *(float4*)(Out + (size_t)r*Ntot + col) = res;
    } else {
      float4 pv = *(const float4*)(Out + (size_t)r*CC + col);
      res.x += pv.x; res.y += pv.y; res.z += pv.z; res.w += pv.w;
      *(float4*)(Out + (size_t)r*CC + col) = res;
    }
  }
}

extern "C" void kernel_launch(void* const* d_in, const int* in_sizes, int n_in,
                              void* d_out, int out_size, void* d_ws, size_t ws_size,
                              hipStream_t stream){
  const float* x      = (const float*)d_in[0];
  const float* n1w    = (const float*)d_in[1];
  const float* n1b    = (const float*)d_in[2];
  const float* qkv_w  = (const float*)d_in[3];
  const float* qkv_b  = (const float*)d_in[4];
  const float* proj_w = (const float*)d_in[5];
  const float* proj_b = (const float*)d_in[6];
  const float* rpb    = (const float*)d_in[7];
  const float* n2w    = (const float*)d_in[8];
  const float* n2b    = (const float*)d_in[9];
  const float* fc1_w  = (const float*)d_in[10];
  const float* fc1_b  = (const float*)d_in[11];
  const float* fc2_w  = (const float*)d_in[12];
  const float* fc2_b  = (const float*)d_in[13];
  float* out = (float*)d_out;

  char* ws = (char*)d_ws;
  const size_t U = (size_t)MR*CC*sizeof(float);      // 59,006,976 B
  float* xw    = (float*)(ws);           // [MR,128]   phase 1-2
  float* qkvb  = (float*)(ws + U);       // [MR,384]   phase 2-3
  float* attno = (float*)(ws);           // [MR,128]   phase 3-4 (aliases xw)
  float* hid   = (float*)(ws);           // [MR,512]   phase 6-7 (aliases xw+qkv)
  float* stats = (float*)(ws + 4*U);     // [MR,2]
  // peak ws usage: 4U + MR*2*4 = ~226 MiB

  const int rowBlocks = (MR + 63)/64;    // 1801
  const int lnBlocks  = (MR + 3)/4;      // 28812

  ln1_gather<<<lnBlocks, 256, 0, stream>>>(x, n1w, n1b, xw);
  gemm<0,384,128><<<dim3(rowBlocks, 6), 256, 0, stream>>>(xw, qkv_w, qkv_b, qkvb,
                                                          nullptr, nullptr, nullptr, nullptr);
  attn_kernel<<<Bc*nWd, 256, 0, stream>>>(qkvb, rpb, attno);
  gemm<1,128,128><<<dim3(rowBlocks, 2), 256, 0, stream>>>(attno, proj_w, proj_b, out,
                                                          x, nullptr, nullptr, nullptr);
  ln2_stats<<<lnBlocks, 256, 0, stream>>>(out, stats);
  gemm<2,512,128><<<dim3(rowBlocks, 8), 256, 0, stream>>>(out, fc1_w, fc1_b, hid,
                                                          nullptr, stats, n2w, n2b);
  gemm<3,128,512><<<dim3(rowBlocks, 2), 256, 0, stream>>>(hid, fc2_w, fc2_b, out,
                                                          nullptr, nullptr, nullptr, nullptr);
}

// Round 4
// 577.409 us; speedup vs baseline: 1.6800x; 1.6800x over previous
//
#include <hip/hip_runtime.h>
#include <math.h>

#define DEVFN __device__ __forceinline__

using short8 = __attribute__((ext_vector_type(8))) short;
using f32x4  = __attribute__((ext_vector_type(4))) float;

constexpr int Bc  = 48;     // batch
constexpr int HH  = 49;     // H = W
constexpr int CC  = 128;    // channels
constexpr int NHd = 4;      // heads
constexpr int HD  = 32;     // head dim
constexpr int SSz = 3;      // shift
constexpr int nWd = 49;     // windows per image
constexpr int NT  = 49;     // tokens per window
constexpr int LL  = HH*HH;  // 2401
constexpr int MR  = Bc*nWd*NT; // 115248 rows

DEVFN unsigned short f2bf(float f){
  unsigned int u = __float_as_uint(f);
  u += 0x7fff + ((u >> 16) & 1);          // RNE
  return (unsigned short)(u >> 16);
}
DEVFN float bf2f(unsigned short h){ return __uint_as_float(((unsigned)h) << 16); }

// map windowed row (b, win, t) -> token index (shift applied); bijection
DEVFN int win_row_to_token(int r){
  int b   = r / (nWd*NT);
  int rem = r - b*(nWd*NT);
  int win = rem / NT;
  int t   = rem - win*NT;
  int hs  = (win/7)*7 + t/7;
  int ws_ = (win%7)*7 + t%7;
  int h = hs + SSz; if (h >= HH) h -= HH;
  int w = ws_ + SSz; if (w >= HH) w -= HH;
  return b*LL + h*HH + w;
}

// region id for shift mask (reference's quirky [nW,nW,N] broadcast reproduced)
DEVFN int rgn(int win, int tok){
  int hh = (win/7)*7 + tok/7;
  int ww = (win%7)*7 + tok%7;
  int rh = hh < 42 ? 0 : (hh < 46 ? 1 : 2);
  int rw = ww < 42 ? 0 : (ww < 46 ? 1 : 2);
  return rh*3 + rw;
}

// -------- LN1 + cyclic shift + window partition gather -> bf16 --------
__global__ __launch_bounds__(256) void ln1_gather(const float* __restrict__ x,
                                                  const float* __restrict__ w,
                                                  const float* __restrict__ b,
                                                  unsigned short* __restrict__ xw){
  int row  = blockIdx.x*4 + (threadIdx.x >> 6);
  int lane = threadIdx.x & 63;
  if (row >= MR) return;
  int token = win_row_to_token(row);
  float2 v = *(const float2*)(x + (size_t)token*CC + lane*2);
  float s  = v.x + v.y;
  float s2 = v.x*v.x + v.y*v.y;
  #pragma unroll
  for (int off = 32; off; off >>= 1){ s += __shfl_xor(s, off); s2 += __shfl_xor(s2, off); }
  float mean = s * (1.f/CC);
  float var  = s2 * (1.f/CC) - mean*mean;
  float rstd = rsqrtf(var + 1e-5f);
  ushort2 o;
  o.x = f2bf((v.x - mean)*rstd*w[lane*2+0] + b[lane*2+0]);
  o.y = f2bf((v.y - mean)*rstd*w[lane*2+1] + b[lane*2+1]);
  *(ushort2*)(xw + (size_t)row*CC + lane*2) = o;
}

// -------- LN2 full normalize (token order) -> bf16 A-matrix for FC1 --------
__global__ __launch_bounds__(256) void ln2norm(const float* __restrict__ x2,
                                               const float* __restrict__ w,
                                               const float* __restrict__ b,
                                               unsigned short* __restrict__ xn){
  int row  = blockIdx.x*4 + (threadIdx.x >> 6);
  int lane = threadIdx.x & 63;
  if (row >= MR) return;
  float2 v = *(const float2*)(x2 + (size_t)row*CC + lane*2);
  float s  = v.x + v.y;
  float s2 = v.x*v.x + v.y*v.y;
  #pragma unroll
  for (int off = 32; off; off >>= 1){ s += __shfl_xor(s, off); s2 += __shfl_xor(s2, off); }
  float mean = s * (1.f/CC);
  float var  = s2 * (1.f/CC) - mean*mean;
  float rstd = rsqrtf(var + 1e-5f);
  ushort2 o;
  o.x = f2bf((v.x - mean)*rstd*w[lane*2+0] + b[lane*2+0]);
  o.y = f2bf((v.y - mean)*rstd*w[lane*2+1] + b[lane*2+1]);
  *(ushort2*)(xn + (size_t)row*CC + lane*2) = o;
}

// -------- windowed attention (bf16 in/out, fp32 math) --------
__global__ __launch_bounds__(256) void attn_kernel(const unsigned short* __restrict__ qkv,
                                                   const float* __restrict__ rpb,
                                                   unsigned short* __restrict__ attno){
  __shared__ float k_s[NHd][NT*HD];
  __shared__ float v_s[NHd][NT*HD];
  __shared__ float rpb_s[169*NHd];
  int win  = blockIdx.x;          // 0..2351
  int h    = threadIdx.x >> 6;    // head = wave
  int lane = threadIdx.x & 63;

  for (int i = threadIdx.x; i < 169*NHd; i += 256) rpb_s[i] = rpb[i];

  const unsigned short* base = qkv + (size_t)win*NT*384;
  for (int c = lane; c < NT*4; c += 64){     // 196 chunks of 8 per tensor
    int j = c >> 2, q8 = (c & 3)*8;
    short8 kv = *(const short8*)(base + j*384 + 128 + h*HD + q8);
    short8 vv = *(const short8*)(base + j*384 + 256 + h*HD + q8);
    #pragma unroll
    for (int e = 0; e < 8; ++e){
      k_s[h][j*HD + q8 + e] = bf2f((unsigned short)kv[e]);
      v_s[h][j*HD + q8 + e] = bf2f((unsigned short)vv[e]);
    }
  }
  __syncthreads();

  int i = lane;
  if (i >= NT) return;

  float q[HD];
  #pragma unroll
  for (int c = 0; c < 4; ++c){
    short8 qv = *(const short8*)(base + i*384 + h*HD + c*8);
    #pragma unroll
    for (int e = 0; e < 8; ++e) q[c*8+e] = bf2f((unsigned short)qv[e]) * 0.17677669529663689f;
  }

  int wmod = win % nWd;
  int yi = i/7, xi = i%7;

  float s[NT];
  #pragma unroll
  for (int j = 0; j < NT; ++j){
    float dot = 0.f;
    #pragma unroll
    for (int d4 = 0; d4 < HD/4; ++d4){
      float4 kv = *(const float4*)&k_s[h][j*HD + d4*4];
      dot = fmaf(q[d4*4+0], kv.x, dot);
      dot = fmaf(q[d4*4+1], kv.y, dot);
      dot = fmaf(q[d4*4+2], kv.z, dot);
      dot = fmaf(q[d4*4+3], kv.w, dot);
    }
    int yj = j/7, xj = j%7;
    int idx = (yi - yj + 6)*13 + (xi - xj + 6);
    float bias = rpb_s[idx*NHd + h];
    float mask = (rgn(wmod, j) != rgn(i, j)) ? -100.f : 0.f;
    s[j] = dot + bias + mask;
  }

  float m = -1e30f;
  #pragma unroll
  for (int j = 0; j < NT; ++j) m = fmaxf(m, s[j]);
  float sum = 0.f;
  #pragma unroll
  for (int j = 0; j < NT; ++j){ s[j] = __expf(s[j]-m); sum += s[j]; }
  float inv = 1.f/sum;

  float o[HD];
  #pragma unroll
  for (int d = 0; d < HD; ++d) o[d] = 0.f;
  #pragma unroll
  for (int j = 0; j < NT; ++j){
    float p = s[j]*inv;
    #pragma unroll
    for (int d4 = 0; d4 < HD/4; ++d4){
      float4 vv = *(const float4*)&v_s[h][j*HD + d4*4];
      o[d4*4+0] = fmaf(p, vv.x, o[d4*4+0]);
      o[d4*4+1] = fmaf(p, vv.y, o[d4*4+1]);
      o[d4*4+2] = fmaf(p, vv.z, o[d4*4+2]);
      o[d4*4+3] = fmaf(p, vv.w, o[d4*4+3]);
    }
  }

  unsigned short* op = attno + ((size_t)win*NT + i)*CC + h*HD;
  #pragma unroll
  for (int d4 = 0; d4 < HD/4; ++d4){
    ushort4 pk;
    pk.x = f2bf(o[d4*4+0]); pk.y = f2bf(o[d4*4+1]);
    pk.z = f2bf(o[d4*4+2]); pk.w = f2bf(o[d4*4+3]);
    *(ushort4*)(op + d4*4) = pk;
  }
}

// -------- bf16 MFMA GEMM: Out = epilogue(A[M,K] @ W[N,K]^T + bias) --------
// MODE 0: qkv  (out bf16 [MR,384])
// MODE 1: proj (out fp32 d_out[token] = acc + bias + X[token]; scatter)
// MODE 2: fc1  (GELU, out bf16 [MR,512])
// MODE 3: fc2  (out fp32 d_out[r] += acc + bias; in-place residual)
template<int MODE, int Ntot, int KK>
__global__ __launch_bounds__(256) void gemm_bf16(const unsigned short* __restrict__ A,
                                                 const float* __restrict__ Wm,
                                                 const float* __restrict__ bias,
                                                 void* __restrict__ OutV,
                                                 const float* __restrict__ X){
  constexpr int BM = 128, BN = 128, BK = 64, LDK = 72;  // +8 pad: 144B row stride
  __shared__ unsigned short As[BM*LDK];
  __shared__ unsigned short Ws[BN*LDK];
  int tid  = threadIdx.x;
  int lane = tid & 63, wid = tid >> 6;
  int wr = wid >> 1, wc = wid & 1;             // 2x2 waves, 64x64 each
  int row0 = blockIdx.x*BM, col0 = blockIdx.y*BN;

  f32x4 acc[4][4] = {};

  for (int k0 = 0; k0 < KK; k0 += BK){
    // stage A (bf16 source): 1024 chunks of 8
    #pragma unroll
    for (int p = 0; p < 4; ++p){
      int idx = p*256 + tid;
      int r = idx >> 3, c8 = (idx & 7)*8;
      int gr = row0 + r;
      short8 v = {};
      if (gr < MR) v = *(const short8*)(A + (size_t)gr*KK + k0 + c8);
      *(short8*)(As + r*LDK + c8) = v;
    }
    // stage W (fp32 source, convert): 2048 chunks of 4
    #pragma unroll
    for (int p = 0; p < 8; ++p){
      int idx = p*256 + tid;
      int r = idx >> 4, c4 = (idx & 15)*4;
      float4 wv = *(const float4*)(Wm + (size_t)(col0 + r)*KK + k0 + c4);
      ushort4 pk;
      pk.x = f2bf(wv.x); pk.y = f2bf(wv.y); pk.z = f2bf(wv.z); pk.w = f2bf(wv.w);
      *(ushort4*)(Ws + r*LDK + c4) = pk;
    }
    __syncthreads();

    int fr = lane & 15, fq = lane >> 4;
    #pragma unroll
    for (int kk = 0; kk < 2; ++kk){
      short8 a[4], b[4];
      #pragma unroll
      for (int m = 0; m < 4; ++m)
        a[m] = *(const short8*)(As + (wr*64 + m*16 + fr)*LDK + kk*32 + fq*8);
      #pragma unroll
      for (int n = 0; n < 4; ++n)
        b[n] = *(const short8*)(Ws + (wc*64 + n*16 + fr)*LDK + kk*32 + fq*8);
      #pragma unroll
      for (int m = 0; m < 4; ++m)
        #pragma unroll
        for (int n = 0; n < 4; ++n)
          acc[m][n] = __builtin_amdgcn_mfma_f32_16x16x32_bf16(a[m], b[n], acc[m][n], 0, 0, 0);
    }
    __syncthreads();
  }

  // epilogue: lane holds C[row = .. + fq*4 + r][col = .. + fr] in acc[m][n][r]
  int fr = lane & 15, fq = lane >> 4;
  #pragma unroll
  for (int m = 0; m < 4; ++m){
    #pragma unroll
    for (int r = 0; r < 4; ++r){
      int grow = row0 + wr*64 + m*16 + fq*4 + r;
      if (grow >= MR) continue;
      int tok = 0;
      if constexpr (MODE == 1) tok = win_row_to_token(grow);
      #pragma unroll
      for (int n = 0; n < 4; ++n){
        int gcol = col0 + wc*64 + n*16 + fr;
        float v = acc[m][n][r] + bias[gcol];
        if constexpr (MODE == 0){
          ((unsigned short*)OutV)[(size_t)grow*Ntot + gcol] = f2bf(v);
        } else if constexpr (MODE == 1){
          ((float*)OutV)[(size_t)tok*CC + gcol] = v + X[(size_t)tok*CC + gcol];
        } else if constexpr (MODE == 2){
          v = 0.5f*v*(1.f + erff(v*0.70710678118654752f));
          ((unsigned short*)OutV)[(size_t)grow*Ntot + gcol] = f2bf(v);
        } else {
          float* p = (float*)OutV + (size_t)grow*CC + gcol;
          *p = *p + v;
        }
      }
    }
  }
}

extern "C" void kernel_launch(void* const* d_in, const int* in_sizes, int n_in,
                              void* d_out, int out_size, void* d_ws, size_t ws_size,
                              hipStream_t stream){
  const float* x      = (const float*)d_in[0];
  const float* n1w    = (const float*)d_in[1];
  const float* n1b    = (const float*)d_in[2];
  const float* qkv_w  = (const float*)d_in[3];
  const float* qkv_b  = (const float*)d_in[4];
  const float* proj_w = (const float*)d_in[5];
  const float* proj_b = (const float*)d_in[6];
  const float* rpb    = (const float*)d_in[7];
  const float* n2w    = (const float*)d_in[8];
  const float* n2b    = (const float*)d_in[9];
  const float* fc1_w  = (const float*)d_in[10];
  const float* fc1_b  = (const float*)d_in[11];
  const float* fc2_w  = (const float*)d_in[12];
  const float* fc2_b  = (const float*)d_in[13];
  float* out = (float*)d_out;

  char* ws = (char*)d_ws;
  const size_t U2 = (size_t)MR*CC*2;                // 29,503,488 B (bf16 [MR,128])
  unsigned short* xw    = (unsigned short*)(ws);            // phase 1-2
  unsigned short* qkvb  = (unsigned short*)(ws + U2);       // [MR,384] phase 2-3
  unsigned short* attno = (unsigned short*)(ws);            // aliases xw (dead)
  unsigned short* xn    = (unsigned short*)(ws + U2);       // aliases qkvb (dead)
  unsigned short* hid   = (unsigned short*)(ws + 4*U2);     // [MR,512] phase 6-7
  // peak ws usage: 8*U2 = 236 MB (fits: R2 used 237 MB)

  const int lnBlocks = (MR + 3)/4;       // 28812
  const int mBlocks  = (MR + 127)/128;   // 901

  ln1_gather<<<lnBlocks, 256, 0, stream>>>(x, n1w, n1b, xw);
  gemm_bf16<0,384,128><<<dim3(mBlocks,3), 256, 0, stream>>>(xw, qkv_w, qkv_b, qkvb, nullptr);
  attn_kernel<<<Bc*nWd, 256, 0, stream>>>(qkvb, rpb, attno);
  gemm_bf16<1,128,128><<<dim3(mBlocks,1), 256, 0, stream>>>(attno, proj_w, proj_b, out, x);
  ln2norm<<<lnBlocks, 256, 0, stream>>>(out, n2w, n2b, xn);
  gemm_bf16<2,512,128><<<dim3(mBlocks,4), 256, 0, stream>>>(xn, fc1_w, fc1_b, hid, nullptr);
  gemm_bf16<3,128,512><<<dim3(mBlocks,1), 256, 0, stream>>>(hid, fc2_w, fc2_b, out, nullptr);
}

// Round 5
// 471.621 us; speedup vs baseline: 2.0568x; 1.2243x over previous
//
#include <hip/hip_runtime.h>
#include <math.h>

#define DEVFN __device__ __forceinline__

using short8 = __attribute__((ext_vector_type(8))) short;
using f32x4  = __attribute__((ext_vector_type(4))) float;

constexpr int Bc  = 48;     // batch
constexpr int HH  = 49;     // H = W
constexpr int CC  = 128;    // channels
constexpr int NHd = 4;      // heads
constexpr int HD  = 32;     // head dim
constexpr int SSz = 3;      // shift
constexpr int nWd = 49;     // windows per image
constexpr int NT  = 49;     // tokens per window
constexpr int LL  = HH*HH;  // 2401
constexpr int MR  = Bc*nWd*NT; // 115248 rows

DEVFN unsigned short f2bf(float f){
  unsigned int u = __float_as_uint(f);
  u += 0x7fff + ((u >> 16) & 1);          // RNE
  return (unsigned short)(u >> 16);
}
DEVFN float bf2f(unsigned short h){ return __uint_as_float(((unsigned)h) << 16); }

// async global->LDS, 16B per lane; LDS dest = wave-uniform base + lane*16
DEVFN void gload16(const unsigned short* g, unsigned short* l){
  __builtin_amdgcn_global_load_lds((const __attribute__((address_space(1))) unsigned int*)g,
                                   (__attribute__((address_space(3))) unsigned int*)l,
                                   16, 0, 0);
}

// map windowed row (b, win, t) -> token index (shift applied); bijection
DEVFN int win_row_to_token(int r){
  int b   = r / (nWd*NT);
  int rem = r - b*(nWd*NT);
  int win = rem / NT;
  int t   = rem - win*NT;
  int hs  = (win/7)*7 + t/7;
  int ws_ = (win%7)*7 + t%7;
  int h = hs + SSz; if (h >= HH) h -= HH;
  int w = ws_ + SSz; if (w >= HH) w -= HH;
  return b*LL + h*HH + w;
}

// region id for shift mask (reference's quirky [nW,nW,N] broadcast reproduced)
DEVFN int rgn(int win, int tok){
  int hh = (win/7)*7 + tok/7;
  int ww = (win%7)*7 + tok%7;
  int rh = hh < 42 ? 0 : (hh < 46 ? 1 : 2);
  int rw = ww < 42 ? 0 : (ww < 46 ? 1 : 2);
  return rh*3 + rw;
}

// -------- weight fp32 -> bf16 pre-convert (once) --------
__global__ __launch_bounds__(256) void wconv(const float* __restrict__ qkv_w,
                                             const float* __restrict__ proj_w,
                                             const float* __restrict__ fc1_w,
                                             const float* __restrict__ fc2_w,
                                             unsigned short* __restrict__ wq,
                                             unsigned short* __restrict__ wp,
                                             unsigned short* __restrict__ w1,
                                             unsigned short* __restrict__ w2){
  int b = blockIdx.x, t = threadIdx.x;
  const float* src; unsigned short* dst; int base;
  if (b < 48)      { src = qkv_w;  dst = wq; base = b*1024; }
  else if (b < 64) { src = proj_w; dst = wp; base = (b-48)*1024; }
  else if (b < 128){ src = fc1_w;  dst = w1; base = (b-64)*1024; }
  else             { src = fc2_w;  dst = w2; base = (b-128)*1024; }
  int i = base + t*4;
  float4 v = *(const float4*)(src + i);
  ushort4 o; o.x=f2bf(v.x); o.y=f2bf(v.y); o.z=f2bf(v.z); o.w=f2bf(v.w);
  *(ushort4*)(dst + i) = o;
}

// -------- LN1 + cyclic shift + window partition gather -> bf16 --------
__global__ __launch_bounds__(256) void ln1_gather(const float* __restrict__ x,
                                                  const float* __restrict__ w,
                                                  const float* __restrict__ b,
                                                  unsigned short* __restrict__ xw){
  int row  = blockIdx.x*4 + (threadIdx.x >> 6);
  int lane = threadIdx.x & 63;
  if (row >= MR) return;
  int token = win_row_to_token(row);
  float2 v = *(const float2*)(x + (size_t)token*CC + lane*2);
  float s  = v.x + v.y;
  float s2 = v.x*v.x + v.y*v.y;
  #pragma unroll
  for (int off = 32; off; off >>= 1){ s += __shfl_xor(s, off); s2 += __shfl_xor(s2, off); }
  float mean = s * (1.f/CC);
  float var  = s2 * (1.f/CC) - mean*mean;
  float rstd = rsqrtf(var + 1e-5f);
  ushort2 o;
  o.x = f2bf((v.x - mean)*rstd*w[lane*2+0] + b[lane*2+0]);
  o.y = f2bf((v.y - mean)*rstd*w[lane*2+1] + b[lane*2+1]);
  *(ushort2*)(xw + (size_t)row*CC + lane*2) = o;
}

// -------- LN2 full normalize -> bf16 A-matrix for FC1 --------
__global__ __launch_bounds__(256) void ln2norm(const float* __restrict__ x2,
                                               const float* __restrict__ w,
                                               const float* __restrict__ b,
                                               unsigned short* __restrict__ xn){
  int row  = blockIdx.x*4 + (threadIdx.x >> 6);
  int lane = threadIdx.x & 63;
  if (row >= MR) return;
  float2 v = *(const float2*)(x2 + (size_t)row*CC + lane*2);
  float s  = v.x + v.y;
  float s2 = v.x*v.x + v.y*v.y;
  #pragma unroll
  for (int off = 32; off; off >>= 1){ s += __shfl_xor(s, off); s2 += __shfl_xor(s2, off); }
  float mean = s * (1.f/CC);
  float var  = s2 * (1.f/CC) - mean*mean;
  float rstd = rsqrtf(var + 1e-5f);
  ushort2 o;
  o.x = f2bf((v.x - mean)*rstd*w[lane*2+0] + b[lane*2+0]);
  o.y = f2bf((v.y - mean)*rstd*w[lane*2+1] + b[lane*2+1]);
  *(ushort2*)(xn + (size_t)row*CC + lane*2) = o;
}

// -------- windowed attention (bf16 in/out, fp32 math) --------
__global__ __launch_bounds__(256) void attn_kernel(const unsigned short* __restrict__ qkv,
                                                   const float* __restrict__ rpb,
                                                   unsigned short* __restrict__ attno){
  __shared__ float k_s[NHd][NT*HD];
  __shared__ float v_s[NHd][NT*HD];
  __shared__ float rpb_s[169*NHd];
  int win  = blockIdx.x;          // 0..2351
  int h    = threadIdx.x >> 6;    // head = wave
  int lane = threadIdx.x & 63;

  for (int i = threadIdx.x; i < 169*NHd; i += 256) rpb_s[i] = rpb[i];

  const unsigned short* base = qkv + (size_t)win*NT*384;
  for (int c = lane; c < NT*4; c += 64){
    int j = c >> 2, q8 = (c & 3)*8;
    short8 kv = *(const short8*)(base + j*384 + 128 + h*HD + q8);
    short8 vv = *(const short8*)(base + j*384 + 256 + h*HD + q8);
    #pragma unroll
    for (int e = 0; e < 8; ++e){
      k_s[h][j*HD + q8 + e] = bf2f((unsigned short)kv[e]);
      v_s[h][j*HD + q8 + e] = bf2f((unsigned short)vv[e]);
    }
  }
  __syncthreads();

  int i = lane;
  if (i >= NT) return;

  float q[HD];
  #pragma unroll
  for (int c = 0; c < 4; ++c){
    short8 qv = *(const short8*)(base + i*384 + h*HD + c*8);
    #pragma unroll
    for (int e = 0; e < 8; ++e) q[c*8+e] = bf2f((unsigned short)qv[e]) * 0.17677669529663689f;
  }

  int wmod = win % nWd;
  int yi = i/7, xi = i%7;

  float s[NT];
  #pragma unroll
  for (int j = 0; j < NT; ++j){
    float dot = 0.f;
    #pragma unroll
    for (int d4 = 0; d4 < HD/4; ++d4){
      float4 kv = *(const float4*)&k_s[h][j*HD + d4*4];
      dot = fmaf(q[d4*4+0], kv.x, dot);
      dot = fmaf(q[d4*4+1], kv.y, dot);
      dot = fmaf(q[d4*4+2], kv.z, dot);
      dot = fmaf(q[d4*4+3], kv.w, dot);
    }
    int yj = j/7, xj = j%7;
    int idx = (yi - yj + 6)*13 + (xi - xj + 6);
    float bias = rpb_s[idx*NHd + h];
    float mask = (rgn(wmod, j) != rgn(i, j)) ? -100.f : 0.f;
    s[j] = dot + bias + mask;
  }

  float m = -1e30f;
  #pragma unroll
  for (int j = 0; j < NT; ++j) m = fmaxf(m, s[j]);
  float sum = 0.f;
  #pragma unroll
  for (int j = 0; j < NT; ++j){ s[j] = __expf(s[j]-m); sum += s[j]; }
  float inv = 1.f/sum;

  float o[HD];
  #pragma unroll
  for (int d = 0; d < HD; ++d) o[d] = 0.f;
  #pragma unroll
  for (int j = 0; j < NT; ++j){
    float p = s[j]*inv;
    #pragma unroll
    for (int d4 = 0; d4 < HD/4; ++d4){
      float4 vv = *(const float4*)&v_s[h][j*HD + d4*4];
      o[d4*4+0] = fmaf(p, vv.x, o[d4*4+0]);
      o[d4*4+1] = fmaf(p, vv.y, o[d4*4+1]);
      o[d4*4+2] = fmaf(p, vv.z, o[d4*4+2]);
      o[d4*4+3] = fmaf(p, vv.w, o[d4*4+3]);
    }
  }

  unsigned short* op = attno + ((size_t)win*NT + i)*CC + h*HD;
  #pragma unroll
  for (int d4 = 0; d4 < HD/4; ++d4){
    ushort4 pk;
    pk.x = f2bf(o[d4*4+0]); pk.y = f2bf(o[d4*4+1]);
    pk.z = f2bf(o[d4*4+2]); pk.w = f2bf(o[d4*4+3]);
    *(ushort4*)(op + d4*4) = pk;
  }
}

// -------- weight-stationary GEMM, K=128 full-resident --------
// Block: 256 rows x full K in LDS (64 KB, swizzled), A-frags hoisted to regs,
// loop N in 64-col chunks (B-frags straight from L2-resident bf16 W).
// MODE 0: qkv  (bf16 out [MR,NTOT])
// MODE 1: proj (fp32 out[tok] = acc + bias + X[tok]; scatter)
// MODE 2: fc1  (GELU, bf16 out)
template<int MODE, int NTOT>
__global__ __launch_bounds__(256, 2) void gemm_k128(const unsigned short* __restrict__ A,
                                                    const unsigned short* __restrict__ Wb,
                                                    const float* __restrict__ bias,
                                                    void* __restrict__ OutV,
                                                    const float* __restrict__ X){
  __shared__ __align__(16) unsigned short As[256*128];   // 64 KB
  int tid = threadIdx.x, lane = tid & 63, w = tid >> 6;
  int fr = lane & 15, fq = lane >> 4;
  int row0 = blockIdx.x * 256;

  // stage A tile (contiguous 64 KB of global); LDS linear, source pre-swizzled
  {
    const unsigned short* Ab = A + (size_t)row0*128;
    #pragma unroll
    for (int i = 0; i < 16; ++i){
      int L   = w*1024 + i*64 + lane;       // LDS chunk index (16B chunks)
      int row = L >> 4;
      int cg  = (L & 15) ^ (row & 15);      // inverse-swizzled global chunk
      gload16(Ab + row*128 + cg*8, As + w*8192 + i*512);
    }
  }
  __syncthreads();

  // hoist A-frags: a[m][kc], row = w*64+m*16+fr, k = kc*32+fq*8 (swizzled read)
  short8 a[4][4];
  #pragma unroll
  for (int m = 0; m < 4; ++m)
    #pragma unroll
    for (int kc = 0; kc < 4; ++kc){
      int row = w*64 + m*16 + fr;
      int cs  = (kc*4 + fq) ^ fr;           // row&15 == fr here
      a[m][kc] = *(const short8*)(As + row*128 + cs*8);
    }

  int tok_[4][4];
  if constexpr (MODE == 1){
    #pragma unroll
    for (int m = 0; m < 4; ++m)
      #pragma unroll
      for (int r = 0; r < 4; ++r){
        int grow = row0 + w*64 + m*16 + fq*4 + r;
        tok_[m][r] = (grow < MR) ? win_row_to_token(grow) : 0;
      }
  }

  for (int c0 = 0; c0 < NTOT; c0 += 64){
    short8 b[4][4];
    #pragma unroll
    for (int n = 0; n < 4; ++n)
      #pragma unroll
      for (int kc = 0; kc < 4; ++kc)
        b[n][kc] = *(const short8*)(Wb + (size_t)(c0 + n*16 + fr)*128 + kc*32 + fq*8);

    f32x4 acc[4][4] = {};
    #pragma unroll
    for (int kc = 0; kc < 4; ++kc)
      #pragma unroll
      for (int m = 0; m < 4; ++m)
        #pragma unroll
        for (int n = 0; n < 4; ++n)
          acc[m][n] = __builtin_amdgcn_mfma_f32_16x16x32_bf16(a[m][kc], b[n][kc], acc[m][n], 0, 0, 0);

    float bv[4];
    #pragma unroll
    for (int n = 0; n < 4; ++n) bv[n] = bias[c0 + n*16 + fr];

    #pragma unroll
    for (int m = 0; m < 4; ++m){
      #pragma unroll
      for (int r = 0; r < 4; ++r){
        int grow = row0 + w*64 + m*16 + fq*4 + r;
        if (grow >= MR) continue;
        #pragma unroll
        for (int n = 0; n < 4; ++n){
          int gcol = c0 + n*16 + fr;
          float v = acc[m][n][r] + bv[n];
          if constexpr (MODE == 0){
            ((unsigned short*)OutV)[(size_t)grow*NTOT + gcol] = f2bf(v);
          } else if constexpr (MODE == 1){
            int tok = tok_[m][r];
            ((float*)OutV)[(size_t)tok*CC + gcol] = v + X[(size_t)tok*CC + gcol];
          } else {
            v = 0.5f*v*(1.f + erff(v*0.70710678118654752f));
            ((unsigned short*)OutV)[(size_t)grow*NTOT + gcol] = f2bf(v);
          }
        }
      }
    }
  }
}

// -------- fc2: [MR,512] @ [128,512]^T, K chunked by 128, acc persistent --------
__global__ __launch_bounds__(256, 2) void gemm_fc2(const unsigned short* __restrict__ A,
                                                   const unsigned short* __restrict__ Wb,
                                                   const float* __restrict__ bias,
                                                   float* __restrict__ Out){
  __shared__ __align__(16) unsigned short As[256*128];   // 64 KB per K-chunk
  int tid = threadIdx.x, lane = tid & 63, w = tid >> 6;
  int fr = lane & 15, fq = lane >> 4;
  int row0 = blockIdx.x * 256;

  f32x4 acc[4][8] = {};   // m x n (64 rows x 128 cols per wave)

  for (int kc0 = 0; kc0 < 4; ++kc0){
    if (kc0) __syncthreads();            // all waves done reading previous As
    const unsigned short* Ab = A + (size_t)row0*512 + kc0*128;
    #pragma unroll
    for (int i = 0; i < 16; ++i){
      int L   = w*1024 + i*64 + lane;
      int row = L >> 4;
      int cg  = (L & 15) ^ (row & 15);
      gload16(Ab + (size_t)row*512 + cg*8, As + w*8192 + i*512);
    }
    __syncthreads();

    #pragma unroll
    for (int kk = 0; kk < 2; ++kk){      // two 64-wide halves of the 128-chunk
      short8 a[4][2];
      #pragma unroll
      for (int m = 0; m < 4; ++m)
        #pragma unroll
        for (int k2 = 0; k2 < 2; ++k2){
          int row = w*64 + m*16 + fr;
          int cs  = (kk*8 + k2*4 + fq) ^ fr;
          a[m][k2] = *(const short8*)(As + row*128 + cs*8);
        }
      short8 b[8][2];
      #pragma unroll
      for (int n = 0; n < 8; ++n)
        #pragma unroll
        for (int k2 = 0; k2 < 2; ++k2)
          b[n][k2] = *(const short8*)(Wb + (size_t)(n*16 + fr)*512 + kc0*128 + kk*64 + k2*32 + fq*8);
      #pragma unroll
      for (int k2 = 0; k2 < 2; ++k2)
        #pragma unroll
        for (int m = 0; m < 4; ++m)
          #pragma unroll
          for (int n = 0; n < 8; ++n)
            acc[m][n] = __builtin_amdgcn_mfma_f32_16x16x32_bf16(a[m][k2], b[n][k2], acc[m][n], 0, 0, 0);
    }
  }

  float bv[8];
  #pragma unroll
  for (int n = 0; n < 8; ++n) bv[n] = bias[n*16 + fr];
  #pragma unroll
  for (int m = 0; m < 4; ++m){
    #pragma unroll
    for (int r = 0; r < 4; ++r){
      int grow = row0 + w*64 + m*16 + fq*4 + r;
      if (grow >= MR) continue;
      #pragma unroll
      for (int n = 0; n < 8; ++n){
        float* p = Out + (size_t)grow*CC + n*16 + fr;
        *p = *p + acc[m][n][r] + bv[n];
      }
    }
  }
}

extern "C" void kernel_launch(void* const* d_in, const int* in_sizes, int n_in,
                              void* d_out, int out_size, void* d_ws, size_t ws_size,
                              hipStream_t stream){
  const float* x      = (const float*)d_in[0];
  const float* n1w    = (const float*)d_in[1];
  const float* n1b    = (const float*)d_in[2];
  const float* qkv_w  = (const float*)d_in[3];
  const float* qkv_b  = (const float*)d_in[4];
  const float* proj_w = (const float*)d_in[5];
  const float* proj_b = (const float*)d_in[6];
  const float* rpb    = (const float*)d_in[7];
  const float* n2w    = (const float*)d_in[8];
  const float* n2b    = (const float*)d_in[9];
  const float* fc1_w  = (const float*)d_in[10];
  const float* fc1_b  = (const float*)d_in[11];
  const float* fc2_w  = (const float*)d_in[12];
  const float* fc2_b  = (const float*)d_in[13];
  float* out = (float*)d_out;

  char* ws = (char*)d_ws;
  const size_t U2 = (size_t)MR*CC*2;                // 29,503,488 B
  unsigned short* xw    = (unsigned short*)(ws);            // [MR,128] bf16
  unsigned short* qkvb  = (unsigned short*)(ws + U2);       // [MR,384] bf16
  unsigned short* attno = (unsigned short*)(ws);            // aliases xw (dead)
  unsigned short* xn    = (unsigned short*)(ws + U2);       // aliases qkvb (dead)
  unsigned short* hid   = (unsigned short*)(ws + 4*U2);     // [MR,512] bf16
  unsigned short* wq    = (unsigned short*)(ws + 8*U2);                 // 49152
  unsigned short* wp    = wq + 49152;                                   // 16384
  unsigned short* w1    = wp + 16384;                                   // 65536
  unsigned short* w2    = w1 + 65536;                                   // 65536
  // peak: 8*U2 + 393 KB = 236.42 MB  (R2 proved ws_size >= 236.95 MB)

  const int lnBlocks = (MR + 3)/4;       // 28812
  const int mB256    = (MR + 255)/256;   // 451

  wconv<<<192, 256, 0, stream>>>(qkv_w, proj_w, fc1_w, fc2_w, wq, wp, w1, w2);
  ln1_gather<<<lnBlocks, 256, 0, stream>>>(x, n1w, n1b, xw);
  gemm_k128<0,384><<<mB256, 256, 0, stream>>>(xw, wq, qkv_b, qkvb, nullptr);
  attn_kernel<<<Bc*nWd, 256, 0, stream>>>(qkvb, rpb, attno);
  gemm_k128<1,128><<<mB256, 256, 0, stream>>>(attno, wp, proj_b, out, x);
  ln2norm<<<lnBlocks, 256, 0, stream>>>(out, n2w, n2b, xn);
  gemm_k128<2,512><<<mB256, 256, 0, stream>>>(xn, w1, fc1_b, hid, nullptr);
  gemm_fc2<<<mB256, 256, 0, stream>>>(hid, w2, fc2_b, out);
}